// Round 15
// baseline (203.816 us; speedup 1.0000x reference)
//
#include <hip/hip_runtime.h>
#include <stdint.h>

typedef unsigned short u16;
typedef __bf16 bf8 __attribute__((ext_vector_type(8)));
typedef float f4 __attribute__((ext_vector_type(4)));

#define S_ 2048
#define D_ 1024
#define H_ 16
#define HD_ 64
#define M_ 4096

__device__ __forceinline__ u16 f2bf(float f) {
  union { float f; uint32_t u; } v; v.f = f;
  uint32_t u = v.u;
  u += 0x7FFF + ((u >> 16) & 1);   // round-to-nearest-even
  return (u16)(u >> 16);
}

__device__ __forceinline__ float b2f(u16 u) {
  union { uint32_t u; float f; } v; v.u = (uint32_t)u << 16; return v.f;
}

__device__ __forceinline__ float fexp2(float x) {
#if __has_builtin(__builtin_amdgcn_exp2f)
  return __builtin_amdgcn_exp2f(x);   // single v_exp_f32
#else
  float r; asm("v_exp_f32 %0, %1" : "=v"(r) : "v"(x)); return r;
#endif
}

// inline-asm 16B load: cannot be sunk/serialized by the register allocator.
__device__ __forceinline__ bf8 gload16(const u16* p) {
  bf8 r;
  asm volatile("global_load_dwordx4 %0, %1, off" : "=v"(r) : "v"(p));
  return r;
}

__device__ __forceinline__ void load_lds16(const void* g, void* l) {
  __builtin_amdgcn_global_load_lds(
      (const __attribute__((address_space(1))) void*)g,
      (__attribute__((address_space(3))) void*)l, 16, 0, 0);
}

// stage one 128x32 A-tile + 128x32 B-tile (bf16) into buf (16KB), swizzled
// source so linear gload_lds dest + XOR'd read side are consistent (rule 21).
__device__ __forceinline__ void stage_ab(
    const u16* __restrict__ A, const u16* __restrict__ B,
    int m0, int n0, int kt, u16* buf, int tid) {
  #pragma unroll
  for (int l = 0; l < 4; ++l) {
    int p = l * 256 + tid;          // 0..1023: 16B units; <512 A, >=512 B
    int q = p & 511;
    int row = q >> 2, c = q & 3;
    int clog = c ^ ((row >> 1) & 3);
    const u16* src = (p >> 9)
        ? (B + (size_t)(n0 + row) * 1024 + kt * 32 + clog * 8)
        : (A + (size_t)(m0 + row) * 1024 + kt * 32 + clog * 8);
    load_lds16(src, buf + p * 8);
  }
}

// ------- fused prep: LN (blocks 0..4095) + weight convert (blocks 4096..) ---
__global__ __launch_bounds__(256) void prep_kernel(
    const float* __restrict__ x, const float* __restrict__ gamma,
    const float* __restrict__ beta, u16* __restrict__ hbf,
    const float* __restrict__ wq, const float* __restrict__ wk,
    const float* __restrict__ wv, const float* __restrict__ wo,
    u16* __restrict__ wqkv, u16* __restrict__ wobf, float* __restrict__ Z) {
  int tid = threadIdx.x;
  if (blockIdx.x < 4096) {
    int row = blockIdx.x;
    int w = tid >> 6, lane = tid & 63;
    const float* xr = x + (size_t)row * D_;
    float lv[4];
    float s = 0.f;
    #pragma unroll
    for (int i = 0; i < 4; ++i) { lv[i] = xr[tid + i * 256]; s += lv[i]; }
    __shared__ float red[8];
    #pragma unroll
    for (int off = 32; off >= 1; off >>= 1) s += __shfl_xor(s, off);
    if (lane == 0) red[w] = s;
    __syncthreads();
    float mean = (red[0] + red[1] + red[2] + red[3]) * (1.f / D_);
    float vs = 0.f;
    #pragma unroll
    for (int i = 0; i < 4; ++i) { float d = lv[i] - mean; vs += d * d; }
    #pragma unroll
    for (int off = 32; off >= 1; off >>= 1) vs += __shfl_xor(vs, off);
    if (lane == 0) red[4 + w] = vs;
    __syncthreads();
    float var = (red[4] + red[5] + red[6] + red[7]) * (1.f / D_);
    float rstd = rsqrtf(var + 1e-5f);
    #pragma unroll
    for (int i = 0; i < 4; ++i) {
      int col = tid + i * 256;
      float y = (lv[i] - mean) * rstd * gamma[col] + beta[col];
      hbf[(size_t)row * D_ + col] = f2bf(y);
    }
  } else {
    int i4 = (blockIdx.x - 4096) * 256 + tid;   // 0 .. 1M-1
    int base = i4 * 4;
    int part = base >> 20;
    int off = base & 0xFFFFF;
    const float* src = part == 0 ? wq : part == 1 ? wk : part == 2 ? wv : wo;
    float4 v = *(const float4*)(src + off);
    ushort4 o;
    o.x = f2bf(v.x); o.y = f2bf(v.y); o.z = f2bf(v.z); o.w = f2bf(v.w);
    if (part < 3) *(ushort4*)(wqkv + base) = o;
    else *(ushort4*)(wobf + off) = o;
    if (i4 < 32 * S_) Z[i4] = (float)(i4 & (S_ - 1));
  }
}

// ---- QKV GEMM: C[4096,3072] = h @ Wqkv^T; ring-3 pipeline, BK=32, 48KB ----
// Q pre-scaled by log2(e)/32; Q,K,V all stored bf16 in [B,H,S,HD] layout.
__global__ __launch_bounds__(256, 3) void gemm_qkv_kernel(
    const u16* __restrict__ A,    // [4096][1024] bf16
    const u16* __restrict__ W,    // [3072][1024] bf16
    const float* __restrict__ bq, const float* __restrict__ bk,
    const float* __restrict__ bv,
    u16* __restrict__ Qb, u16* __restrict__ Kb, u16* __restrict__ Vb) {
  __shared__ u16 smem[3 * 8192];   // 3 bufs x (A 8KB + B 8KB)
  const int tid = threadIdx.x;
  const int w = tid >> 6, lane = tid & 63;
  const int wr = w >> 1, wc = w & 1;
  const int lr = lane & 15, hi = lane >> 4;
  const int kswz = (hi ^ ((lr >> 1) & 3)) * 8;   // swizzled 16B slot (in u16)

  // XCD super-chunk: 2x4 XCD grid over 32m x 24n tiles; per-XCD 16m x 6n
  int bid = blockIdx.x;
  int xcd = bid & 7, i = bid >> 3;        // i 0..95
  int rc = xcd >> 2, cc = xcd & 3;
  const int m0 = (rc * 16 + (i & 15)) * 128;
  const int n0 = (cc * 6 + (i >> 4)) * 128;

  f4 acc[4][4];
  f4 zero = {0.f, 0.f, 0.f, 0.f};
  #pragma unroll
  for (int i2 = 0; i2 < 4; ++i2)
    #pragma unroll
    for (int j = 0; j < 4; ++j) acc[i2][j] = zero;

  stage_ab(A, W, m0, n0, 0, smem, tid);
  stage_ab(A, W, m0, n0, 1, smem + 8192, tid);

  for (int t = 0; t < 32; ++t) {
    if (t < 31) asm volatile("s_waitcnt vmcnt(4)\n\ts_barrier" ::: "memory");
    else        asm volatile("s_waitcnt vmcnt(0)\n\ts_barrier" ::: "memory");
    const u16* As = smem + (t % 3) * 8192;
    const u16* Bs = As + 4096;
    bf8 av[4], bvv[4];
    #pragma unroll
    for (int i2 = 0; i2 < 4; ++i2)
      av[i2] = *(const bf8*)&As[(wr * 64 + i2 * 16 + lr) * 32 + kswz];
    #pragma unroll
    for (int j = 0; j < 4; ++j)
      bvv[j] = *(const bf8*)&Bs[(wc * 64 + j * 16 + lr) * 32 + kswz];
    if (t < 30) stage_ab(A, W, m0, n0, t + 2, smem + ((t + 2) % 3) * 8192, tid);
    __builtin_amdgcn_s_setprio(1);
    #pragma unroll
    for (int i2 = 0; i2 < 4; ++i2)
      #pragma unroll
      for (int j = 0; j < 4; ++j)
        acc[i2][j] = __builtin_amdgcn_mfma_f32_16x16x32_bf16(
            av[i2], bvv[j], acc[i2][j], 0, 0, 0);
    __builtin_amdgcn_s_setprio(0);
  }

  // unified epilogue: part block-uniform; Q scaled, all bf16
  const int part = n0 >> 10;
  const int colbase = n0 & 1023;
  const float SCQ = 0.04508422002778011f;   // log2(e)/sqrt(1024)
  const float* bias_p = part == 0 ? bq : (part == 1 ? bk : bv);
  u16* dst = part == 0 ? Qb : (part == 1 ? Kb : Vb);
  const float scale = part == 0 ? SCQ : 1.f;
  #pragma unroll
  for (int i2 = 0; i2 < 4; ++i2)
    #pragma unroll
    for (int j = 0; j < 4; ++j)
      #pragma unroll
      for (int r = 0; r < 4; ++r) {
        int m = m0 + wr * 64 + i2 * 16 + hi * 4 + r;
        int col = colbase + wc * 64 + j * 16 + lr;
        float val = (acc[i2][j][r] + bias_p[col]) * scale;
        int b = m >> 11, s = m & 2047;
        int hh = col >> 6, d = col & 63;
        dst[((size_t)(b * H_ + hh) * S_ + s) * HD_ + d] = f2bf(val);
      }
}

// ------- scores: uniform supertiles (64 q x 256 k), XCD-local bh, atomic Z --
// All 16 fragment loads via inline-asm global_load_dwordx4 (cannot be
// serialized by RA) -> single vmcnt(0) -> sched_barrier -> compute.
__global__ __launch_bounds__(256, 4) void scores_z_kernel(
    const u16* __restrict__ Qb, const u16* __restrict__ Kb,
    float* __restrict__ Z, float* __restrict__ Ed) {
  int bid = blockIdx.x;               // 0..4607
  int idx = bid >> 3;                 // 0..575
  int bh = (bid & 7) * 4 + (idx / 144);
  int t = idx - (idx / 144) * 144;    // 0..143
  int g = 0;
  while (true) { int cnt = 4 * (8 - g); if (t < cnt) break; t -= cnt; ++g; }
  const int qb = g * 4 + (t & 3);     // 64-row strip
  const int c = g + (t >> 2);         // 256-col chunk
  const bool diag = (c == g);

  const int tid = threadIdx.x;
  const int w = tid >> 6, lane = tid & 63;
  const int lr = lane & 15, hi = lane >> 4, lkb = hi * 8;
  const u16* Qh = Qb + (size_t)bh * S_ * HD_;
  const u16* Kh = Kb + (size_t)bh * S_ * HD_;
  const int q0 = qb * 64;

  // issue ALL 16 loads back-to-back (asm volatile: order preserved, no sink)
  bf8 a[4][2], kb[4][2];
  #pragma unroll
  for (int g2 = 0; g2 < 4; ++g2) {
    a[g2][0] = gload16(&Qh[(q0 + g2 * 16 + lr) * 64 + lkb]);
    a[g2][1] = gload16(&Qh[(q0 + g2 * 16 + lr) * 64 + 32 + lkb]);
  }
  #pragma unroll
  for (int i = 0; i < 4; ++i) {
    int kt = c * 16 + w + i * 4;      // wave-interleaved: 16 tiles / 4 waves
    kb[i][0] = gload16(&Kh[(kt * 16 + lr) * 64 + lkb]);
    kb[i][1] = gload16(&Kh[(kt * 16 + lr) * 64 + 32 + lkb]);
  }
  asm volatile("s_waitcnt vmcnt(0)" ::: "memory");
  __builtin_amdgcn_sched_barrier(0);  // rule 18: fence MFMA below the waitcnt

  float zacc[4][4];
  #pragma unroll
  for (int g2 = 0; g2 < 4; ++g2)
    #pragma unroll
    for (int r = 0; r < 4; ++r) zacc[g2][r] = 0.f;

  #pragma unroll
  for (int i = 0; i < 4; ++i) {
    int kt = c * 16 + w + i * 4;
    int kcol = kt * 16 + lr;
    f4 cc[4];
    #pragma unroll
    for (int g2 = 0; g2 < 4; ++g2) {
      f4 z4 = {0.f, 0.f, 0.f, 0.f};
      z4 = __builtin_amdgcn_mfma_f32_16x16x32_bf16(a[g2][0], kb[i][0], z4, 0, 0, 0);
      cc[g2] = __builtin_amdgcn_mfma_f32_16x16x32_bf16(a[g2][1], kb[i][1], z4, 0, 0, 0);
    }
    if (diag) {
      #pragma unroll
      for (int g2 = 0; g2 < 4; ++g2) {
        #pragma unroll
        for (int r = 0; r < 4; ++r) {
          float e = fexp2(cc[g2][r]);
          int qrow = q0 + g2 * 16 + hi * 4 + r;
          zacc[g2][r] += (kcol >= qrow) ? e : 0.f;
          if (kcol == qrow) Ed[(size_t)bh * S_ + qrow] = e;
        }
      }
    } else {
      #pragma unroll
      for (int g2 = 0; g2 < 4; ++g2) {
        #pragma unroll
        for (int r = 0; r < 4; ++r)
          zacc[g2][r] += fexp2(cc[g2][r]);
      }
    }
  }

  __shared__ float Zp[4][64];
  #pragma unroll
  for (int g2 = 0; g2 < 4; ++g2) {
    #pragma unroll
    for (int r = 0; r < 4; ++r) {
      float v = zacc[g2][r];
      v += __shfl_xor(v, 1);
      v += __shfl_xor(v, 2);
      v += __shfl_xor(v, 4);
      v += __shfl_xor(v, 8);
      if (lr == 0) Zp[w][g2 * 16 + hi * 4 + r] = v;
    }
  }
  __syncthreads();
  if (tid < 64) {
    float z = Zp[0][tid] + Zp[1][tid] + Zp[2][tid] + Zp[3][tid];
    atomicAdd(&Z[(size_t)bh * S_ + q0 + tid], z);
  }
}

// ---------------- V prefix-sum chain (16-row chunks, bf16 V) ----------------
#define NC_ 128   // chunks per bh (16 rows each)

__global__ __launch_bounds__(64) void vchunk_kernel(
    const u16* __restrict__ Vb, float* __restrict__ csum) {
  int bh = blockIdx.y, c = blockIdx.x;
  int d = threadIdx.x;
  const u16* vp = Vb + ((size_t)bh * S_ + c * 16) * HD_ + d;
  float s = 0.f;
  #pragma unroll
  for (int r = 0; r < 16; ++r) s += b2f(vp[r * HD_]);
  csum[((size_t)bh * NC_ + c) * HD_ + d] = s;
}

// per-bh exclusive scan; all loads issued independently, scan in registers
__global__ __launch_bounds__(256) void vprefix_kernel(float* __restrict__ csum) {
  int bh = blockIdx.x;
  int d = threadIdx.x & 63;
  int qt = threadIdx.x >> 6;
  __shared__ float tot[4][64];
  float v[32];
  #pragma unroll
  for (int c = 0; c < 32; ++c)
    v[c] = csum[((size_t)bh * NC_ + qt * 32 + c) * HD_ + d];
  float run = 0.f;
  #pragma unroll
  for (int c = 0; c < 32; ++c) { float t = v[c]; v[c] = run; run += t; }
  tot[qt][d] = run;
  __syncthreads();
  float off = 0.f;
  #pragma unroll
  for (int p = 0; p < 4; ++p) if (p < qt) off += tot[p][d];
  #pragma unroll
  for (int c = 0; c < 32; ++c)
    csum[((size_t)bh * NC_ + qt * 32 + c) * HD_ + d] = v[c] + off;
}

__global__ __launch_bounds__(64) void attn_out_kernel(
    const u16* __restrict__ Vb, const float* __restrict__ csum,
    const float* __restrict__ Z, const float* __restrict__ Ed,
    u16* __restrict__ concat) {
  int bh = blockIdx.y, c = blockIdx.x;
  int d = threadIdx.x;
  int b = bh >> 4, h = bh & 15;
  float run = csum[((size_t)bh * NC_ + c) * HD_ + d];
  #pragma unroll
  for (int r = 0; r < 16; ++r) {
    int s = c * 16 + r;
    float v = b2f(Vb[((size_t)bh * S_ + s) * HD_ + d]);
    float z = Z[(size_t)bh * S_ + s];
    float e = Ed[(size_t)bh * S_ + s];
    float a = (run + e * v) / z;
    concat[(size_t)(b * S_ + s) * D_ + h * HD_ + d] = f2bf(a);
    run += v;
  }
}

// -- output GEMM: out = x + concat @ wo^T + bo; ring-3 pipeline, BK=32 --
__global__ __launch_bounds__(256, 3) void gemm_out_kernel(
    const u16* __restrict__ A,    // concat bf16 [4096][1024]
    const u16* __restrict__ W,    // wo bf16 [1024][1024]
    const float* __restrict__ x, const float* __restrict__ bo,
    float* __restrict__ out) {
  __shared__ u16 smem[3 * 8192];
  const int tid = threadIdx.x;
  const int w = tid >> 6, lane = tid & 63;
  const int wr = w >> 1, wc = w & 1;
  const int lr = lane & 15, hi = lane >> 4;
  const int kswz = (hi ^ ((lr >> 1) & 3)) * 8;

  // XCD chunk: 32m x 8n tiles; per-XCD 4m x all-n
  int bid = blockIdx.x;
  int xcd = bid & 7, i = bid >> 3;        // i 0..31
  const int m0 = (xcd * 4 + (i & 3)) * 128;
  const int n0 = (i >> 2) * 128;

  f4 acc[4][4];
  f4 zero = {0.f, 0.f, 0.f, 0.f};
  #pragma unroll
  for (int i2 = 0; i2 < 4; ++i2)
    #pragma unroll
    for (int j = 0; j < 4; ++j) acc[i2][j] = zero;

  stage_ab(A, W, m0, n0, 0, smem, tid);
  stage_ab(A, W, m0, n0, 1, smem + 8192, tid);

  for (int t = 0; t < 32; ++t) {
    if (t < 31) asm volatile("s_waitcnt vmcnt(4)\n\ts_barrier" ::: "memory");
    else        asm volatile("s_waitcnt vmcnt(0)\n\ts_barrier" ::: "memory");
    const u16* As = smem + (t % 3) * 8192;
    const u16* Bs = As + 4096;
    bf8 av[4], bvv[4];
    #pragma unroll
    for (int i2 = 0; i2 < 4; ++i2)
      av[i2] = *(const bf8*)&As[(wr * 64 + i2 * 16 + lr) * 32 + kswz];
    #pragma unroll
    for (int j = 0; j < 4; ++j)
      bvv[j] = *(const bf8*)&Bs[(wc * 64 + j * 16 + lr) * 32 + kswz];
    if (t < 30) stage_ab(A, W, m0, n0, t + 2, smem + ((t + 2) % 3) * 8192, tid);
    __builtin_amdgcn_s_setprio(1);
    #pragma unroll
    for (int i2 = 0; i2 < 4; ++i2)
      #pragma unroll
      for (int j = 0; j < 4; ++j)
        acc[i2][j] = __builtin_amdgcn_mfma_f32_16x16x32_bf16(
            av[i2], bvv[j], acc[i2][j], 0, 0, 0);
    __builtin_amdgcn_s_setprio(0);
  }

  #pragma unroll
  for (int i2 = 0; i2 < 4; ++i2)
    #pragma unroll
    for (int j = 0; j < 4; ++j)
      #pragma unroll
      for (int r = 0; r < 4; ++r) {
        int m = m0 + wr * 64 + i2 * 16 + hi * 4 + r;
        int n = n0 + wc * 64 + j * 16 + lr;
        size_t oi = (size_t)m * D_ + n;
        out[oi] = x[oi] + acc[i2][j][r] + bo[n];
      }
}

extern "C" void kernel_launch(void* const* d_in, const int* in_sizes, int n_in,
                              void* d_out, int out_size, void* d_ws, size_t ws_size,
                              hipStream_t stream) {
  (void)in_sizes; (void)n_in; (void)out_size; (void)ws_size;
  const float* x     = (const float*)d_in[0];
  const float* wq    = (const float*)d_in[1];
  const float* bq    = (const float*)d_in[2];
  const float* wk    = (const float*)d_in[3];
  const float* bk    = (const float*)d_in[4];
  const float* wv    = (const float*)d_in[5];
  const float* bv    = (const float*)d_in[6];
  const float* wo    = (const float*)d_in[7];
  const float* bo    = (const float*)d_in[8];
  const float* gamma = (const float*)d_in[9];
  const float* beta  = (const float*)d_in[10];
  float* out = (float*)d_out;

  char* ws = (char*)d_ws;
  u16* hbf    = (u16*)(ws);
  u16* wqkv   = (u16*)(ws + (8u << 20));
  u16* wobf   = (u16*)(ws + (14u << 20));
  u16* Qb     = (u16*)(ws + (16u << 20));
  u16* Kb     = (u16*)(ws + (24u << 20));
  u16* Vb     = (u16*)(ws + (32u << 20));     // bf16 V (8 MB)
  float* Z    = (float*)(ws + (48u << 20));
  float* Ed   = (float*)(ws + (48u << 20) + (256u << 10));
  float* csum = (float*)(ws);                 // aliases hbf (dead after QKV GEMM)
  u16* concat = (u16*)(ws + (16u << 20));     // aliases Qb (dead after scores)

  prep_kernel<<<dim3(8192), dim3(256), 0, stream>>>(
      x, gamma, beta, hbf, wq, wk, wv, wo, wqkv, wobf, Z);
  gemm_qkv_kernel<<<dim3(768), dim3(256), 0, stream>>>(hbf, wqkv, bq, bk, bv,
                                                       Qb, Kb, Vb);
  scores_z_kernel<<<dim3(4608), dim3(256), 0, stream>>>(Qb, Kb, Z, Ed);
  vchunk_kernel<<<dim3(NC_, 32), dim3(64), 0, stream>>>(Vb, csum);
  vprefix_kernel<<<dim3(32), dim3(256), 0, stream>>>(csum);
  attn_out_kernel<<<dim3(NC_, 32), dim3(64), 0, stream>>>(Vb, csum, Z, Ed, concat);
  gemm_out_kernel<<<dim3(256), dim3(256), 0, stream>>>(concat, wobf, x, bo, out);
}